// Round 1
// baseline (170.119 us; speedup 1.0000x reference)
//
#include <hip/hip_runtime.h>
#include <hip/hip_bf16.h>

#define N_HEADS 16
#define HEAD_DIM 64
#define SEQ_LEN 2048

typedef __bf16 bf16x8 __attribute__((ext_vector_type(8)));
typedef float f32x4 __attribute__((ext_vector_type(4)));

// One workgroup: one head, 64 q-rows. 4 waves x 16 q-rows.
// Per wave: Q[16x64] in registers (bf16 A-frags), loop over KV tiles of 32.
//   S = QK^T via 2x2 mfma_f32_16x16x32_bf16, online softmax in C/D layout,
//   P bounced through swizzled LDS (D-layout write -> A-frag read),
//   O += P*V via 4 mfma (V B-frags loaded scalar from global, L2-resident).
__global__ void attn_alibi_kernel(const float* __restrict__ q,
                                  const float* __restrict__ k,
                                  const float* __restrict__ v,
                                  float* __restrict__ out) {
    const int tid  = threadIdx.x;
    const int wave = tid >> 6;
    const int lane = tid & 63;
    const int col  = lane & 15;  // N index in C/D; M row index in A-frag reads
    const int g    = lane >> 4;  // K-group index

    const int h     = blockIdx.y;
    const int qbase = blockIdx.x * 64 + wave * 16;

    const float* qh = q + (size_t)h * SEQ_LEN * HEAD_DIM;
    const float* kh = k + (size_t)h * SEQ_LEN * HEAD_DIM;
    const float* vh = v + (size_t)h * SEQ_LEN * HEAD_DIM;
    float*       oh = out + (size_t)h * SEQ_LEN * HEAD_DIM;

    // Per-wave double-buffered P tile: 16 rows x 32 cols bf16 = 1KB each.
    __shared__ alignas(16) unsigned char p_lds_raw[4][2][1024];

    const float LOG2E  = 1.4426950408889634f;
    const float scale2 = 0.125f * LOG2E;                    // 1/sqrt(64) * log2(e)
    const float slope  = exp2f(-0.5f * (float)(h + 1));     // 2^(-8(h+1)/16)
    const float slope2 = slope * LOG2E;

    // ---- Q A-fragments: lane holds Q[qbase+col][c*32 + g*8 + b] ----
    bf16x8 qf[2];
    {
        const float* qr = qh + (size_t)(qbase + col) * HEAD_DIM + g * 8;
        #pragma unroll
        for (int c = 0; c < 2; ++c) {
            #pragma unroll
            for (int b = 0; b < 8; ++b) qf[c][b] = (__bf16)qr[c * 32 + b];
        }
    }

    // ALiBi per-lane constants: c0[jt][r] = slope2 * (jt*16+col - (qbase+g*4+r))
    float c0[2][4];
    #pragma unroll
    for (int jt = 0; jt < 2; ++jt)
        #pragma unroll
        for (int r = 0; r < 4; ++r)
            c0[jt][r] = slope2 * (float)(jt * 16 + col - (qbase + g * 4 + r));

    float m[4], l[4];
    f32x4 acc[4];
    #pragma unroll
    for (int r = 0; r < 4; ++r) { m[r] = -1e30f; l[r] = 0.0f; }
    #pragma unroll
    for (int dt = 0; dt < 4; ++dt) acc[dt] = (f32x4)0.0f;

    for (int kb = 0; kb < SEQ_LEN; kb += 32) {
        // ---- S = Q K^T for two 16-col tiles ----
        f32x4 sacc[2];
        sacc[0] = (f32x4)0.0f;
        sacc[1] = (f32x4)0.0f;
        #pragma unroll
        for (int jt = 0; jt < 2; ++jt) {
            const float* kr = kh + (size_t)(kb + jt * 16 + col) * HEAD_DIM + g * 8;
            #pragma unroll
            for (int c = 0; c < 2; ++c) {
                bf16x8 kf;
                #pragma unroll
                for (int b = 0; b < 8; ++b) kf[b] = (__bf16)kr[c * 32 + b];
                sacc[jt] = __builtin_amdgcn_mfma_f32_16x16x32_bf16(qf[c], kf, sacc[jt], 0, 0, 0);
            }
        }

        // ---- scale + alibi (base-2 domain) ----
        const float skb = slope2 * (float)kb;
        float s[2][4];
        #pragma unroll
        for (int jt = 0; jt < 2; ++jt)
            #pragma unroll
            for (int r = 0; r < 4; ++r)
                s[jt][r] = sacc[jt][r] * scale2 + (c0[jt][r] + skb);

        // ---- online softmax: row max over 32 cols (16-lane groups) ----
        float alpha[4], p0[4], p1[4], rs[4];
        #pragma unroll
        for (int r = 0; r < 4; ++r) {
            float x = fmaxf(s[0][r], s[1][r]);
            x = fmaxf(x, __shfl_xor(x, 1));
            x = fmaxf(x, __shfl_xor(x, 2));
            x = fmaxf(x, __shfl_xor(x, 4));
            x = fmaxf(x, __shfl_xor(x, 8));
            float mn = fmaxf(m[r], x);
            alpha[r] = __builtin_amdgcn_exp2f(m[r] - mn);
            m[r] = mn;
            p0[r] = __builtin_amdgcn_exp2f(s[0][r] - mn);
            p1[r] = __builtin_amdgcn_exp2f(s[1][r] - mn);
            float y = p0[r] + p1[r];
            y += __shfl_xor(y, 1);
            y += __shfl_xor(y, 2);
            y += __shfl_xor(y, 4);
            y += __shfl_xor(y, 8);
            rs[r] = y;
        }
        #pragma unroll
        for (int r = 0; r < 4; ++r) l[r] = l[r] * alpha[r] + rs[r];
        #pragma unroll
        for (int dt = 0; dt < 4; ++dt)
            #pragma unroll
            for (int r = 0; r < 4; ++r) acc[dt][r] *= alpha[r];

        // ---- P: D-layout -> LDS (XOR swizzled) -> A-frag ----
        unsigned char* pb = p_lds_raw[wave][(kb >> 5) & 1];
        #pragma unroll
        for (int r = 0; r < 4; ++r) {
            int row = g * 4 + r;
            int swz = (row & 7) << 4;
            int b0 = (row * 64 + col * 2) ^ swz;
            int b1 = (row * 64 + (16 + col) * 2) ^ swz;
            *(__bf16*)(pb + b0) = (__bf16)p0[r];
            *(__bf16*)(pb + b1) = (__bf16)p1[r];
        }
        asm volatile("s_waitcnt lgkmcnt(0)" ::: "memory");
        bf16x8 pf;
        {
            int byte = (col * 64 + g * 16) ^ ((col & 7) << 4);
            pf = *(const bf16x8*)(pb + byte);
        }

        // ---- O += P V : V B-frags direct from global (L2-resident) ----
        #pragma unroll
        for (int dt = 0; dt < 4; ++dt) {
            const float* vr = vh + (size_t)(kb + g * 8) * HEAD_DIM + dt * 16 + col;
            bf16x8 vf;
            #pragma unroll
            for (int b = 0; b < 8; ++b) vf[b] = (__bf16)vr[b * HEAD_DIM];
            acc[dt] = __builtin_amdgcn_mfma_f32_16x16x32_bf16(pf, vf, acc[dt], 0, 0, 0);
        }
    }

    // ---- epilogue: divide by l, store fp32 ----
    #pragma unroll
    for (int r = 0; r < 4; ++r) {
        float inv = 1.0f / l[r];
        float* orow = oh + (size_t)(qbase + g * 4 + r) * HEAD_DIM + col;
        #pragma unroll
        for (int dt = 0; dt < 4; ++dt)
            orow[dt * 16] = acc[dt][r] * inv;
    }
}

extern "C" void kernel_launch(void* const* d_in, const int* in_sizes, int n_in,
                              void* d_out, int out_size, void* d_ws, size_t ws_size,
                              hipStream_t stream) {
    const float* q = (const float*)d_in[0];
    const float* k = (const float*)d_in[1];
    const float* v = (const float*)d_in[2];
    float* out = (float*)d_out;

    dim3 grid(SEQ_LEN / 64, N_HEADS, 1);
    dim3 block(256, 1, 1);
    attn_alibi_kernel<<<grid, block, 0, stream>>>(q, k, v, out);
}

// Round 4
// 94.350 us; speedup vs baseline: 1.8031x; 1.8031x over previous
//
#include <hip/hip_runtime.h>
#include <hip/hip_bf16.h>
#include <stdint.h>

#define N_HEADS 16
#define HEAD_DIM 64
#define SEQ_LEN 2048
#define KVBLK 32
#define NTILES (SEQ_LEN / KVBLK)

typedef __bf16 bf16x8 __attribute__((ext_vector_type(8)));
typedef float f32x4 __attribute__((ext_vector_type(4)));

// One workgroup: one head, 64 q-rows (4 waves x 16 rows). KV tiles of 32 rows
// staged in LDS (double-buffered, shared by all 4 waves):
//   K : row-major bf16 [32][64], addr = row*128 + (off ^ ((row&7)<<4))
//       (row stride 128 > max key 112, so add==xor, bijective)
//   Vt: TRANSPOSED bf16 [64 cols][32 rows]; 64-byte rows, so the swizzle is
//       FULL-ADDRESS XOR: addr = (vc*64 + off) ^ ((vc&7)<<4)  — bijective
//       (bit 6 of the key folds into a row-index permutation applied the same
//       way on write and read; ADD-form overflowed and collided rows - R2/R3 bug)
// Staging split issue-early/write-late (T14): global->reg loads for tile t+1
// issue right after QK^T of tile t; LDS write lands after PV; 1 barrier/tile.
__global__ __launch_bounds__(256, 2)
void attn_alibi_kernel(const float* __restrict__ q,
                       const float* __restrict__ k,
                       const float* __restrict__ v,
                       float* __restrict__ out) {
    const int tid  = threadIdx.x;
    const int wave = tid >> 6;
    const int lane = tid & 63;
    const int col  = lane & 15;  // n index in C/D layouts; m row in A-frag reads
    const int g    = lane >> 4;  // k-group index

    const int h     = blockIdx.y;
    const int qbase = blockIdx.x * 64 + wave * 16;

    const float* qh = q + (size_t)h * SEQ_LEN * HEAD_DIM;
    const float* kh = k + (size_t)h * SEQ_LEN * HEAD_DIM;
    const float* vh = v + (size_t)h * SEQ_LEN * HEAD_DIM;
    float*       oh = out + (size_t)h * SEQ_LEN * HEAD_DIM;

    __shared__ alignas(16) __bf16 k_lds[2][KVBLK * HEAD_DIM];   // 2 x 4 KB
    __shared__ alignas(16) __bf16 vt_lds[2][HEAD_DIM * KVBLK];  // 2 x 4 KB (transposed)
    __shared__ alignas(16) unsigned char p_lds[4][1024];        // per-wave P bounce

    const float LOG2E  = 1.4426950408889634f;
    const float scale2 = 0.125f * LOG2E;                 // 1/sqrt(64) * log2(e)
    const float slope  = exp2f(-0.5f * (float)(h + 1));  // 2^(-8(h+1)/16)
    const float slope2 = slope * LOG2E;

    // ---- Q A-fragments: lane holds Q[qbase+col][c*32 + g*8 + b] ----
    bf16x8 qf[2];
    {
        const float* qr = qh + (size_t)(qbase + col) * HEAD_DIM + g * 8;
        #pragma unroll
        for (int c = 0; c < 2; ++c)
            #pragma unroll
            for (int b = 0; b < 8; ++b) qf[c][b] = (__bf16)qr[c * 32 + b];
    }

    // ALiBi per-lane constants
    float c0[2][4];
    #pragma unroll
    for (int jt = 0; jt < 2; ++jt)
        #pragma unroll
        for (int r = 0; r < 4; ++r)
            c0[jt][r] = slope2 * (float)(jt * 16 + col - (qbase + g * 4 + r));

    float m[4], l[4];
    f32x4 acc[4];
    #pragma unroll
    for (int r = 0; r < 4; ++r) { m[r] = -1e30f; l[r] = 0.0f; }
    #pragma unroll
    for (int dt = 0; dt < 4; ++dt) acc[dt] = (f32x4)0.0f;

    // ---- K staging: thread -> K[krow][kcol..kcol+7], coalesced f32x4 pair ----
    const int krow = tid >> 3;          // 0..31
    const int kcol = (tid & 7) * 8;     // 0..56 step 8
    const float* ksrc = kh + (size_t)krow * HEAD_DIM + kcol;
    char* kdst = (char*)k_lds + krow * 128 + ((kcol * 2) ^ ((krow & 7) << 4));

    // ---- V staging (transposed): thread -> column vc, rows vr..vr+7 ----
    // Global loads coalesced (lanes span 64 consecutive floats per j).
    // LDS write: one contiguous 16B chunk, FULL-ADDRESS XOR swizzle.
    const int vc = tid & 63;            // 0..63
    const int vr = (tid >> 6) * 8;      // 0,8,16,24
    const float* vsrc = vh + (size_t)vr * HEAD_DIM + vc;
    char* vtdst = (char*)vt_lds + (((vc * 64) + (vr * 2)) ^ ((vc & 7) << 4));

    f32x4 kr0, kr1;
    float vv[8];

    // ---- prologue: stage tile 0 ----
    kr0 = *(const f32x4*)(ksrc);
    kr1 = *(const f32x4*)(ksrc + 4);
    #pragma unroll
    for (int j = 0; j < 8; ++j) vv[j] = vsrc[(size_t)j * HEAD_DIM];
    {
        bf16x8 kb16, vb16;
        #pragma unroll
        for (int b = 0; b < 4; ++b) { kb16[b] = (__bf16)kr0[b]; kb16[4 + b] = (__bf16)kr1[b]; }
        #pragma unroll
        for (int j = 0; j < 8; ++j) vb16[j] = (__bf16)vv[j];
        *(bf16x8*)(kdst)  = kb16;
        *(bf16x8*)(vtdst) = vb16;
    }
    __syncthreads();

    for (int t = 0; t < NTILES; ++t) {
        const int kb  = t * KVBLK;
        const int buf = t & 1;
        const char* kbuf  = (const char*)k_lds[buf];
        const char* vtbuf = (const char*)vt_lds[buf];

        // ---- S = Q K^T (K B-frags from swizzled LDS) ----
        f32x4 sacc[2];
        sacc[0] = (f32x4)0.0f;
        sacc[1] = (f32x4)0.0f;
        #pragma unroll
        for (int jt = 0; jt < 2; ++jt) {
            const int row = jt * 16 + col;
            #pragma unroll
            for (int c = 0; c < 2; ++c) {
                bf16x8 kf = *(const bf16x8*)(kbuf + row * 128
                                             + ((c * 64 + g * 16) ^ ((row & 7) << 4)));
                sacc[jt] = __builtin_amdgcn_mfma_f32_16x16x32_bf16(qf[c], kf, sacc[jt], 0, 0, 0);
            }
        }

        // ---- issue next-tile staging loads (latency hides under softmax+PV) ----
        if (t + 1 < NTILES) {
            const float* ks = ksrc + (size_t)(t + 1) * KVBLK * HEAD_DIM;
            const float* vs = vsrc + (size_t)(t + 1) * KVBLK * HEAD_DIM;
            kr0 = *(const f32x4*)(ks);
            kr1 = *(const f32x4*)(ks + 4);
            #pragma unroll
            for (int j = 0; j < 8; ++j) vv[j] = vs[(size_t)j * HEAD_DIM];
        }

        // ---- scale + alibi (base-2 domain) ----
        const float skb = slope2 * (float)kb;
        float s[2][4];
        #pragma unroll
        for (int jt = 0; jt < 2; ++jt)
            #pragma unroll
            for (int r = 0; r < 4; ++r)
                s[jt][r] = sacc[jt][r] * scale2 + (c0[jt][r] + skb);

        // ---- online softmax (16-lane-group row reductions) ----
        float alpha[4], p0[4], p1[4], rs[4];
        #pragma unroll
        for (int r = 0; r < 4; ++r) {
            float x = fmaxf(s[0][r], s[1][r]);
            x = fmaxf(x, __shfl_xor(x, 1));
            x = fmaxf(x, __shfl_xor(x, 2));
            x = fmaxf(x, __shfl_xor(x, 4));
            x = fmaxf(x, __shfl_xor(x, 8));
            float mn = fmaxf(m[r], x);
            alpha[r] = __builtin_amdgcn_exp2f(m[r] - mn);
            m[r] = mn;
            p0[r] = __builtin_amdgcn_exp2f(s[0][r] - mn);
            p1[r] = __builtin_amdgcn_exp2f(s[1][r] - mn);
            float y = p0[r] + p1[r];
            y += __shfl_xor(y, 1);
            y += __shfl_xor(y, 2);
            y += __shfl_xor(y, 4);
            y += __shfl_xor(y, 8);
            rs[r] = y;
        }
        #pragma unroll
        for (int r = 0; r < 4; ++r) l[r] = l[r] * alpha[r] + rs[r];
        #pragma unroll
        for (int dt = 0; dt < 4; ++dt)
            #pragma unroll
            for (int r = 0; r < 4; ++r) acc[dt][r] *= alpha[r];

        // ---- P: D-layout -> per-wave LDS (swizzled) -> A-frag ----
        unsigned char* pb = p_lds[wave];
        #pragma unroll
        for (int r = 0; r < 4; ++r) {
            int row = g * 4 + r;
            int swz = (row & 7) << 4;
            *(__bf16*)(pb + ((row * 64 + col * 2) ^ swz))        = (__bf16)p0[r];
            *(__bf16*)(pb + ((row * 64 + (16 + col) * 2) ^ swz)) = (__bf16)p1[r];
        }
        asm volatile("s_waitcnt lgkmcnt(0)" ::: "memory");
        bf16x8 pf = *(const bf16x8*)(pb + ((col * 64 + g * 16) ^ ((col & 7) << 4)));

        // ---- O += P V : V B-frags are contiguous rows of transposed Vt ----
        #pragma unroll
        for (int dt = 0; dt < 4; ++dt) {
            const int vrow = dt * 16 + col;
            bf16x8 vf = *(const bf16x8*)(vtbuf
                            + ((vrow * 64 + g * 16) ^ ((vrow & 7) << 4)));
            acc[dt] = __builtin_amdgcn_mfma_f32_16x16x32_bf16(pf, vf, acc[dt], 0, 0, 0);
        }

        // ---- write next tile into the other LDS buffer ----
        if (t + 1 < NTILES) {
            bf16x8 kb16, vb16;
            #pragma unroll
            for (int b = 0; b < 4; ++b) { kb16[b] = (__bf16)kr0[b]; kb16[4 + b] = (__bf16)kr1[b]; }
            #pragma unroll
            for (int j = 0; j < 8; ++j) vb16[j] = (__bf16)vv[j];
            *(bf16x8*)(kdst  + ((t + 1) & 1) * 4096) = kb16;
            *(bf16x8*)(vtdst + ((t + 1) & 1) * 4096) = vb16;
        }
        __syncthreads();
    }

    // ---- epilogue ----
    #pragma unroll
    for (int r = 0; r < 4; ++r) {
        float inv = 1.0f / l[r];
        float* orow = oh + (size_t)(qbase + g * 4 + r) * HEAD_DIM + col;
        #pragma unroll
        for (int dt = 0; dt < 4; ++dt)
            orow[dt * 16] = acc[dt][r] * inv;
    }
}

extern "C" void kernel_launch(void* const* d_in, const int* in_sizes, int n_in,
                              void* d_out, int out_size, void* d_ws, size_t ws_size,
                              hipStream_t stream) {
    const float* q = (const float*)d_in[0];
    const float* k = (const float*)d_in[1];
    const float* v = (const float*)d_in[2];
    float* out = (float*)d_out;

    dim3 grid(SEQ_LEN / 64, N_HEADS, 1);
    dim3 block(256, 1, 1);
    attn_alibi_kernel<<<grid, block, 0, stream>>>(q, k, v, out);
}

// Round 5
// 87.389 us; speedup vs baseline: 1.9467x; 1.0797x over previous
//
#include <hip/hip_runtime.h>
#include <hip/hip_bf16.h>
#include <stdint.h>

#define N_HEADS 16
#define HEAD_DIM 64
#define SEQ_LEN 2048
#define KVBLK 32
#define HALF_LEN (SEQ_LEN / 2)
#define NTILES (HALF_LEN / KVBLK)   // 32 tiles per half-stream

typedef __bf16 bf16x8 __attribute__((ext_vector_type(8)));
typedef float f32x4 __attribute__((ext_vector_type(4)));

// 8-wave WG, intra-WG KV split. Waves 0-3 ("half 0") process KV[0:1024],
// waves 4-7 ("half 1") KV[1024:2048], for the SAME 64 q-rows
// (wave w4 = wave&3 owns q-rows qbase..qbase+15). Each half has its own
// double-buffered K/Vt LDS stream (addressing identical to the verified R4
// kernel). After the loop the halves merge unnormalized (m,l,O) partials via
// LDS (flash combine, base-2 domain); half 0 stores the output.
//   K : row-major bf16 [32][64], addr = row*128 + (off ^ ((row&7)<<4))
//   Vt: transposed bf16, FULL-ADDRESS XOR: addr = (vc*64 + off) ^ ((vc&7)<<4)
// LDS map (40960 B):
//   [0,16K)    k_lds   [half][dbuf][4096]     (merge overlays this region)
//   [16K,32K)  vt_lds  [half][dbuf][4096]
//   [32K,40K)  p_lds   [wave][1024]
__global__ __launch_bounds__(512, 4)
void attn_alibi_kernel(const float* __restrict__ q,
                       const float* __restrict__ k,
                       const float* __restrict__ v,
                       float* __restrict__ out) {
    const int tid  = threadIdx.x;
    const int wave = tid >> 6;
    const int lane = tid & 63;
    const int col  = lane & 15;
    const int g    = lane >> 4;
    const int half = wave >> 2;     // 0: KV[0:1024), 1: KV[1024:2048)
    const int w4   = wave & 3;

    const int h      = blockIdx.y;
    const int qbase  = blockIdx.x * 64 + w4 * 16;
    const int kstart = half * HALF_LEN;

    const float* qh = q + (size_t)h * SEQ_LEN * HEAD_DIM;
    const float* kh = k + (size_t)h * SEQ_LEN * HEAD_DIM;
    const float* vh = v + (size_t)h * SEQ_LEN * HEAD_DIM;
    float*       oh = out + (size_t)h * SEQ_LEN * HEAD_DIM;

    __shared__ alignas(16) char smem[40960];
    char* kbase  = smem + half * 8192;
    char* vtbase = smem + 16384 + half * 8192;
    unsigned char* pb = (unsigned char*)smem + 32768 + wave * 1024;

    const float LOG2E  = 1.4426950408889634f;
    const float scale2 = 0.125f * LOG2E;
    const float slope  = exp2f(-0.5f * (float)(h + 1));
    const float slope2 = slope * LOG2E;

    // ---- Q A-fragments (both halves load the same rows; L1/L2-hit) ----
    bf16x8 qf[2];
    {
        const float* qr = qh + (size_t)(qbase + col) * HEAD_DIM + g * 8;
        #pragma unroll
        for (int c = 0; c < 2; ++c)
            #pragma unroll
            for (int b = 0; b < 8; ++b) qf[c][b] = (__bf16)qr[c * 32 + b];
    }

    // ALiBi per-lane constants
    float c0[2][4];
    #pragma unroll
    for (int jt = 0; jt < 2; ++jt)
        #pragma unroll
        for (int r = 0; r < 4; ++r)
            c0[jt][r] = slope2 * (float)(jt * 16 + col - (qbase + g * 4 + r));

    float m[4], l[4];
    f32x4 acc[4];
    #pragma unroll
    for (int r = 0; r < 4; ++r) { m[r] = -1e30f; l[r] = 0.0f; }
    #pragma unroll
    for (int dt = 0; dt < 4; ++dt) acc[dt] = (f32x4)0.0f;

    // ---- staging (256 threads per half stage that half's stream) ----
    const int hid  = tid & 255;
    const int krow = hid >> 3;
    const int kcol = (hid & 7) * 8;
    const float* ksrc = kh + (size_t)(kstart + krow) * HEAD_DIM + kcol;
    char* kdst = kbase + krow * 128 + ((kcol * 2) ^ ((krow & 7) << 4));

    const int vc = hid & 63;
    const int vr = (hid >> 6) * 8;
    const float* vsrc = vh + (size_t)(kstart + vr) * HEAD_DIM + vc;
    char* vtdst = vtbase + (((vc * 64) + (vr * 2)) ^ ((vc & 7) << 4));

    f32x4 kr0, kr1;
    float vv[8];

    // ---- prologue: stage tile 0 of this half's stream ----
    kr0 = *(const f32x4*)(ksrc);
    kr1 = *(const f32x4*)(ksrc + 4);
    #pragma unroll
    for (int j = 0; j < 8; ++j) vv[j] = vsrc[(size_t)j * HEAD_DIM];
    {
        bf16x8 kb16, vb16;
        #pragma unroll
        for (int b = 0; b < 4; ++b) { kb16[b] = (__bf16)kr0[b]; kb16[4 + b] = (__bf16)kr1[b]; }
        #pragma unroll
        for (int j = 0; j < 8; ++j) vb16[j] = (__bf16)vv[j];
        *(bf16x8*)(kdst)  = kb16;
        *(bf16x8*)(vtdst) = vb16;
    }
    __syncthreads();

    for (int t = 0; t < NTILES; ++t) {
        const int kb  = kstart + t * KVBLK;
        const int buf = t & 1;
        const char* kbuf  = kbase + buf * 4096;
        const char* vtbuf = vtbase + buf * 4096;

        // ---- S = Q K^T ----
        f32x4 sacc[2];
        sacc[0] = (f32x4)0.0f;
        sacc[1] = (f32x4)0.0f;
        #pragma unroll
        for (int jt = 0; jt < 2; ++jt) {
            const int row = jt * 16 + col;
            #pragma unroll
            for (int c = 0; c < 2; ++c) {
                bf16x8 kf = *(const bf16x8*)(kbuf + row * 128
                                             + ((c * 64 + g * 16) ^ ((row & 7) << 4)));
                sacc[jt] = __builtin_amdgcn_mfma_f32_16x16x32_bf16(qf[c], kf, sacc[jt], 0, 0, 0);
            }
        }

        // ---- issue next-tile staging loads ----
        if (t + 1 < NTILES) {
            const float* ks = ksrc + (size_t)(t + 1) * KVBLK * HEAD_DIM;
            const float* vs = vsrc + (size_t)(t + 1) * KVBLK * HEAD_DIM;
            kr0 = *(const f32x4*)(ks);
            kr1 = *(const f32x4*)(ks + 4);
            #pragma unroll
            for (int j = 0; j < 8; ++j) vv[j] = vs[(size_t)j * HEAD_DIM];
        }

        // ---- scale + alibi (base-2) ----
        const float skb = slope2 * (float)kb;
        float s[2][4];
        #pragma unroll
        for (int jt = 0; jt < 2; ++jt)
            #pragma unroll
            for (int r = 0; r < 4; ++r)
                s[jt][r] = sacc[jt][r] * scale2 + (c0[jt][r] + skb);

        // ---- online softmax ----
        float alpha[4], p0[4], p1[4], rs[4];
        #pragma unroll
        for (int r = 0; r < 4; ++r) {
            float x = fmaxf(s[0][r], s[1][r]);
            x = fmaxf(x, __shfl_xor(x, 1));
            x = fmaxf(x, __shfl_xor(x, 2));
            x = fmaxf(x, __shfl_xor(x, 4));
            x = fmaxf(x, __shfl_xor(x, 8));
            float mn = fmaxf(m[r], x);
            alpha[r] = __builtin_amdgcn_exp2f(m[r] - mn);
            m[r] = mn;
            p0[r] = __builtin_amdgcn_exp2f(s[0][r] - mn);
            p1[r] = __builtin_amdgcn_exp2f(s[1][r] - mn);
            float y = p0[r] + p1[r];
            y += __shfl_xor(y, 1);
            y += __shfl_xor(y, 2);
            y += __shfl_xor(y, 4);
            y += __shfl_xor(y, 8);
            rs[r] = y;
        }
        #pragma unroll
        for (int r = 0; r < 4; ++r) l[r] = l[r] * alpha[r] + rs[r];
        #pragma unroll
        for (int dt = 0; dt < 4; ++dt)
            #pragma unroll
            for (int r = 0; r < 4; ++r) acc[dt][r] *= alpha[r];

        // ---- P bounce through per-wave LDS ----
        #pragma unroll
        for (int r = 0; r < 4; ++r) {
            int row = g * 4 + r;
            int swz = (row & 7) << 4;
            *(__bf16*)(pb + ((row * 64 + col * 2) ^ swz))        = (__bf16)p0[r];
            *(__bf16*)(pb + ((row * 64 + (16 + col) * 2) ^ swz)) = (__bf16)p1[r];
        }
        asm volatile("s_waitcnt lgkmcnt(0)" ::: "memory");
        bf16x8 pf = *(const bf16x8*)(pb + ((col * 64 + g * 16) ^ ((col & 7) << 4)));

        // ---- O += P V ----
        #pragma unroll
        for (int dt = 0; dt < 4; ++dt) {
            const int vrow = dt * 16 + col;
            bf16x8 vf = *(const bf16x8*)(vtbuf
                            + ((vrow * 64 + g * 16) ^ ((vrow & 7) << 4)));
            acc[dt] = __builtin_amdgcn_mfma_f32_16x16x32_bf16(pf, vf, acc[dt], 0, 0, 0);
        }

        // ---- write next tile into the other LDS buffer ----
        if (t + 1 < NTILES) {
            bf16x8 kb16, vb16;
            #pragma unroll
            for (int b = 0; b < 4; ++b) { kb16[b] = (__bf16)kr0[b]; kb16[4 + b] = (__bf16)kr1[b]; }
            #pragma unroll
            for (int j = 0; j < 8; ++j) vb16[j] = (__bf16)vv[j];
            *(bf16x8*)(kdst  + ((t + 1) & 1) * 4096) = kb16;
            *(bf16x8*)(vtdst + ((t + 1) & 1) * 4096) = vb16;
        }
        __syncthreads();
    }

    // ---- merge the two halves (flash combine, base-2 domain) ----
    float* eacc = (float*)smem;            // [w4][16 q][64 d]
    float* eml  = (float*)(smem + 16384);  // [w4][16 q][2]

    if (half == 1) {
        #pragma unroll
        for (int r = 0; r < 4; ++r) {
            const int qrow = g * 4 + r;
            #pragma unroll
            for (int dt = 0; dt < 4; ++dt)
                eacc[w4 * 1024 + qrow * 64 + dt * 16 + col] = acc[dt][r];
            if (col == 0) {
                eml[(w4 * 16 + qrow) * 2 + 0] = m[r];
                eml[(w4 * 16 + qrow) * 2 + 1] = l[r];
            }
        }
    }
    __syncthreads();
    if (half == 0) {
        #pragma unroll
        for (int r = 0; r < 4; ++r) {
            const int qrow = g * 4 + r;
            float m2 = eml[(w4 * 16 + qrow) * 2 + 0];
            float l2 = eml[(w4 * 16 + qrow) * 2 + 1];
            float mm = fmaxf(m[r], m2);
            float a1 = __builtin_amdgcn_exp2f(m[r] - mm);
            float a2 = __builtin_amdgcn_exp2f(m2 - mm);
            float inv = 1.0f / (l[r] * a1 + l2 * a2);
            float* orow = oh + (size_t)(qbase + qrow) * HEAD_DIM + col;
            #pragma unroll
            for (int dt = 0; dt < 4; ++dt) {
                float o2 = eacc[w4 * 1024 + qrow * 64 + dt * 16 + col];
                orow[dt * 16] = (acc[dt][r] * a1 + o2 * a2) * inv;
            }
        }
    }
}

extern "C" void kernel_launch(void* const* d_in, const int* in_sizes, int n_in,
                              void* d_out, int out_size, void* d_ws, size_t ws_size,
                              hipStream_t stream) {
    const float* q = (const float*)d_in[0];
    const float* k = (const float*)d_in[1];
    const float* v = (const float*)d_in[2];
    float* out = (float*)d_out;

    dim3 grid(SEQ_LEN / 64, N_HEADS, 1);
    dim3 block(512, 1, 1);
    attn_alibi_kernel<<<grid, block, 0, stream>>>(q, k, v, out);
}

// Round 6
// 56.323 us; speedup vs baseline: 3.0204x; 1.5516x over previous
//
#include <hip/hip_runtime.h>
#include <hip/hip_bf16.h>
#include <stdint.h>

#define N_HEADS 16
#define HEAD_DIM 64
#define SEQ_LEN 2048
#define KVBLK 32
#define HALF_LEN (SEQ_LEN / 2)
#define NTILES (HALF_LEN / KVBLK)   // 32 tiles per half-stream

typedef __bf16 bf16x8 __attribute__((ext_vector_type(8)));
typedef float f32x4 __attribute__((ext_vector_type(4)));
typedef unsigned int u32x4 __attribute__((ext_vector_type(4)));

static __device__ __forceinline__ unsigned pkbf(float a, float b) {
    union { __bf16 h[2]; unsigned u; } t;
    t.h[0] = (__bf16)a; t.h[1] = (__bf16)b;
    return t.u;
}

// 8-wave WG, intra-WG KV split (waves 0-3: KV[0:1024), waves 4-7: KV[1024:2048)),
// 64 q-rows per WG, wave w4=wave&3 owns q-rows qbase..qbase+15.
//
// SWAPPED QK^T: sacc = mfma(A=K-frag, B=Q-frag) gives S^T — lane (col,g) holds
// S[q=qbase+col][k=kb+jt*16+g*4+r]. Softmax is per-lane scalar (one q-row/lane):
// in-register reduce over 8 regs + shfl_xor(16,32) across g-groups. No P-LDS
// bounce: P packs to 4 bf16x2 words and a fixed 4-lane shfl permutation builds
// the PV B-frag (P^T[k=g*8+b][q=col]). PV: acc[dt] = mfma(A=V^T-frag, B=P^T)
// accumulates O^T: lane holds O[q=qbase+col][d=dt*16+g*4+r] -> f32x4 stores.
//   K : row-major bf16 [32][64], addr = row*128 + (off ^ ((row&7)<<4))
//   Vt: transposed bf16, FULL-ADDRESS XOR: addr = (vc*64 + off) ^ ((vc&7)<<4)
// LDS (32768 B): [0,16K) k[half][dbuf][4096] (merge overlays), [16K,32K) vt.
__global__ __launch_bounds__(512, 4)
void attn_alibi_kernel(const float* __restrict__ q,
                       const float* __restrict__ k,
                       const float* __restrict__ v,
                       float* __restrict__ out) {
    const int tid  = threadIdx.x;
    const int wave = tid >> 6;
    const int lane = tid & 63;
    const int col  = lane & 15;
    const int g    = lane >> 4;
    const int half = wave >> 2;
    const int w4   = wave & 3;

    const int h      = blockIdx.y;
    const int qbase  = blockIdx.x * 64 + w4 * 16;
    const int kstart = half * HALF_LEN;

    const float* qh = q + (size_t)h * SEQ_LEN * HEAD_DIM;
    const float* kh = k + (size_t)h * SEQ_LEN * HEAD_DIM;
    const float* vh = v + (size_t)h * SEQ_LEN * HEAD_DIM;
    float*       oh = out + (size_t)h * SEQ_LEN * HEAD_DIM;

    __shared__ alignas(16) char smem[32768];
    char* kbase  = smem + half * 8192;
    char* vtbase = smem + 16384 + half * 8192;

    const float LOG2E  = 1.4426950408889634f;
    const float scale2 = 0.125f * LOG2E;
    const float slope  = exp2f(-0.5f * (float)(h + 1));
    const float slope2 = slope * LOG2E;

    // ---- Q B-fragments: lane holds Q[qbase+col][c*32 + g*8 + b] ----
    bf16x8 qf[2];
    {
        const float* qr = qh + (size_t)(qbase + col) * HEAD_DIM + g * 8;
        #pragma unroll
        for (int c = 0; c < 2; ++c)
            #pragma unroll
            for (int b = 0; b < 8; ++b) qf[c][b] = (__bf16)qr[c * 32 + b];
    }

    // ALiBi: alibi(q,k) = slope2*(k-q); cb = slope2*((jt*16+g*4+r) - (qbase+col))
    float cb[2][4];
    #pragma unroll
    for (int jt = 0; jt < 2; ++jt)
        #pragma unroll
        for (int r = 0; r < 4; ++r)
            cb[jt][r] = slope2 * (float)(jt * 16 + g * 4 + r - (qbase + col));

    float m = -1e30f, l = 0.0f;
    f32x4 acc[4];
    #pragma unroll
    for (int dt = 0; dt < 4; ++dt) acc[dt] = (f32x4)0.0f;

    // ---- staging (256 threads per half stage that half's stream) ----
    const int hid  = tid & 255;
    const int krow = hid >> 3;
    const int kcol = (hid & 7) * 8;
    const float* ksrc = kh + (size_t)(kstart + krow) * HEAD_DIM + kcol;
    char* kdst = kbase + krow * 128 + ((kcol * 2) ^ ((krow & 7) << 4));

    const int vc = hid & 63;
    const int vr = (hid >> 6) * 8;
    const float* vsrc = vh + (size_t)(kstart + vr) * HEAD_DIM + vc;
    char* vtdst = vtbase + (((vc * 64) + (vr * 2)) ^ ((vc & 7) << 4));

    f32x4 kr0, kr1;
    float vv[8];

    // ---- prologue: stage tile 0 ----
    kr0 = *(const f32x4*)(ksrc);
    kr1 = *(const f32x4*)(ksrc + 4);
    #pragma unroll
    for (int j = 0; j < 8; ++j) vv[j] = vsrc[(size_t)j * HEAD_DIM];
    {
        bf16x8 kb16, vb16;
        #pragma unroll
        for (int b = 0; b < 4; ++b) { kb16[b] = (__bf16)kr0[b]; kb16[4 + b] = (__bf16)kr1[b]; }
        #pragma unroll
        for (int j = 0; j < 8; ++j) vb16[j] = (__bf16)vv[j];
        *(bf16x8*)(kdst)  = kb16;
        *(bf16x8*)(vtdst) = vb16;
    }
    __syncthreads();

    for (int t = 0; t < NTILES; ++t) {
        const int kb  = kstart + t * KVBLK;
        const int buf = t & 1;
        const char* kbuf  = kbase + buf * 4096;
        const char* vtbuf = vtbase + buf * 4096;

        // ---- S^T = K Q^T (swapped operands) ----
        f32x4 sacc[2];
        sacc[0] = (f32x4)0.0f;
        sacc[1] = (f32x4)0.0f;
        #pragma unroll
        for (int jt = 0; jt < 2; ++jt) {
            const int row = jt * 16 + col;
            #pragma unroll
            for (int c = 0; c < 2; ++c) {
                bf16x8 kf = *(const bf16x8*)(kbuf + row * 128
                                             + ((c * 64 + g * 16) ^ ((row & 7) << 4)));
                sacc[jt] = __builtin_amdgcn_mfma_f32_16x16x32_bf16(kf, qf[c], sacc[jt], 0, 0, 0);
            }
        }

        // ---- issue next-tile staging loads ----
        if (t + 1 < NTILES) {
            const float* ks = ksrc + (size_t)(t + 1) * KVBLK * HEAD_DIM;
            const float* vs = vsrc + (size_t)(t + 1) * KVBLK * HEAD_DIM;
            kr0 = *(const f32x4*)(ks);
            kr1 = *(const f32x4*)(ks + 4);
            #pragma unroll
            for (int j = 0; j < 8; ++j) vv[j] = vs[(size_t)j * HEAD_DIM];
        }

        // ---- scale + alibi (base-2); lane holds s[k-local] for its q-row ----
        const float skb = slope2 * (float)kb;
        float s[2][4];
        #pragma unroll
        for (int jt = 0; jt < 2; ++jt)
            #pragma unroll
            for (int r = 0; r < 4; ++r)
                s[jt][r] = sacc[jt][r] * scale2 + (cb[jt][r] + skb);

        // ---- online softmax: scalar per lane ----
        float x = s[0][0];
        #pragma unroll
        for (int jt = 0; jt < 2; ++jt)
            #pragma unroll
            for (int r = 0; r < 4; ++r) x = fmaxf(x, s[jt][r]);
        x = fmaxf(x, __shfl_xor(x, 16));
        x = fmaxf(x, __shfl_xor(x, 32));
        float mn    = fmaxf(m, x);
        float alpha = __builtin_amdgcn_exp2f(m - mn);
        m = mn;
        float p[2][4], y = 0.0f;
        #pragma unroll
        for (int jt = 0; jt < 2; ++jt)
            #pragma unroll
            for (int r = 0; r < 4; ++r) {
                p[jt][r] = __builtin_amdgcn_exp2f(s[jt][r] - mn);
                y += p[jt][r];
            }
        y += __shfl_xor(y, 16);
        y += __shfl_xor(y, 32);
        l = l * alpha + y;
        #pragma unroll
        for (int dt = 0; dt < 4; ++dt) acc[dt] *= alpha;

        // ---- pack P to bf16 pairs: pk[jt][h2] covers k = jt*16+g*4+2*h2+{0,1}
        unsigned pk00 = pkbf(p[0][0], p[0][1]);
        unsigned pk01 = pkbf(p[0][2], p[0][3]);
        unsigned pk10 = pkbf(p[1][0], p[1][1]);
        unsigned pk11 = pkbf(p[1][2], p[1][3]);

        // ---- permute to PV B-frag: lane (col,g) slot j needs k=g*8+2j+{0,1}
        //      = src lane col+32*(g&1)+16*(j>>1), reg (jt=g>>1, h2=j&1)
        const int srcA = col + ((g & 1) << 5);
        const int srcB = srcA + 16;
        unsigned a00 = __shfl(pk00, srcA), a01 = __shfl(pk01, srcA);
        unsigned a10 = __shfl(pk10, srcA), a11 = __shfl(pk11, srcA);
        unsigned b00 = __shfl(pk00, srcB), b01 = __shfl(pk01, srcB);
        unsigned b10 = __shfl(pk10, srcB), b11 = __shfl(pk11, srcB);
        const bool hi = g >= 2;
        u32x4 pu;
        pu[0] = hi ? a10 : a00;
        pu[1] = hi ? a11 : a01;
        pu[2] = hi ? b10 : b00;
        pu[3] = hi ? b11 : b01;
        bf16x8 pf = __builtin_bit_cast(bf16x8, pu);

        // ---- O^T += V^T P^T : A = V^T-frag (existing Vt read), B = P^T ----
        #pragma unroll
        for (int dt = 0; dt < 4; ++dt) {
            const int vrow = dt * 16 + col;
            bf16x8 vf = *(const bf16x8*)(vtbuf
                            + ((vrow * 64 + g * 16) ^ ((vrow & 7) << 4)));
            acc[dt] = __builtin_amdgcn_mfma_f32_16x16x32_bf16(vf, pf, acc[dt], 0, 0, 0);
        }

        // ---- write next tile into the other LDS buffer ----
        if (t + 1 < NTILES) {
            bf16x8 kb16, vb16;
            #pragma unroll
            for (int b = 0; b < 4; ++b) { kb16[b] = (__bf16)kr0[b]; kb16[4 + b] = (__bf16)kr1[b]; }
            #pragma unroll
            for (int j = 0; j < 8; ++j) vb16[j] = (__bf16)vv[j];
            *(bf16x8*)(kdst  + ((t + 1) & 1) * 4096) = kb16;
            *(bf16x8*)(vtdst + ((t + 1) & 1) * 4096) = vb16;
        }
        __syncthreads();
    }

    // ---- merge halves (flash combine in O^T layout, base-2 domain) ----
    float* eacc = (float*)smem;            // [w4][q=col 16][d 64]
    float* eml  = (float*)(smem + 16384);  // [w4*16+col]*2

    if (half == 1) {
        #pragma unroll
        for (int dt = 0; dt < 4; ++dt)
            *(f32x4*)(eacc + w4 * 1024 + col * 64 + dt * 16 + g * 4) = acc[dt];
        if (g == 0) {
            eml[(w4 * 16 + col) * 2 + 0] = m;
            eml[(w4 * 16 + col) * 2 + 1] = l;
        }
    }
    __syncthreads();
    if (half == 0) {
        float m2 = eml[(w4 * 16 + col) * 2 + 0];
        float l2 = eml[(w4 * 16 + col) * 2 + 1];
        float mm = fmaxf(m, m2);
        float a1 = __builtin_amdgcn_exp2f(m - mm);
        float a2 = __builtin_amdgcn_exp2f(m2 - mm);
        float inv = 1.0f / (l * a1 + l2 * a2);
        float* orow = oh + (size_t)(qbase + col) * HEAD_DIM;
        #pragma unroll
        for (int dt = 0; dt < 4; ++dt) {
            f32x4 o2 = *(const f32x4*)(eacc + w4 * 1024 + col * 64 + dt * 16 + g * 4);
            f32x4 res = (acc[dt] * a1 + o2 * a2) * inv;
            *(f32x4*)(orow + dt * 16 + g * 4) = res;
        }
    }
}

extern "C" void kernel_launch(void* const* d_in, const int* in_sizes, int n_in,
                              void* d_out, int out_size, void* d_ws, size_t ws_size,
                              hipStream_t stream) {
    const float* q = (const float*)d_in[0];
    const float* k = (const float*)d_in[1];
    const float* v = (const float*)d_in[2];
    float* out = (float*)d_out;

    dim3 grid(SEQ_LEN / 64, N_HEADS, 1);
    dim3 block(512, 1, 1);
    attn_alibi_kernel<<<grid, block, 0, stream>>>(q, k, v, out);
}

// Round 7
// 52.054 us; speedup vs baseline: 3.2681x; 1.0820x over previous
//
#include <hip/hip_runtime.h>
#include <hip/hip_bf16.h>
#include <stdint.h>

#define N_HEADS 16
#define HEAD_DIM 64
#define SEQ_LEN 2048
#define KVBLK 32
#define HALF_LEN (SEQ_LEN / 2)
#define NTILES (HALF_LEN / KVBLK)   // 32 tiles per half-stream

typedef __bf16 bf16x8 __attribute__((ext_vector_type(8)));
typedef __bf16 bf16x4 __attribute__((ext_vector_type(4)));
typedef short  s16x4  __attribute__((ext_vector_type(4)));
typedef float  f32x4  __attribute__((ext_vector_type(4)));
typedef unsigned int u32x4 __attribute__((ext_vector_type(4)));

#if __has_builtin(__builtin_amdgcn_mfma_f32_16x16x16bf16_1k)
#define HAVE_MFMA16 1
#else
#define HAVE_MFMA16 0
#endif

static __device__ __forceinline__ unsigned pkbf(float a, float b) {
    union { __bf16 h[2]; unsigned u; } t;
    t.h[0] = (__bf16)a; t.h[1] = (__bf16)b;
    return t.u;
}

// 8-wave WG, intra-WG KV split (waves 0-3: KV[0:1024), waves 4-7: KV[1024:2048)),
// 64 q-rows per WG, wave w4=wave&3 owns q-rows qbase..qbase+15.
//
// SWAPPED QK^T: sacc = mfma_16x16x32(A=K-frag, B=Q-frag) = S^T — lane (col,g)
// holds S[q=qbase+col][k=kb+jt*16+g*4+r]. Softmax per-lane scalar + 2 shfl_xor.
//
// ZERO-SHUFFLE PV: the K=16 MFMA (mfma_f32_16x16x16bf16_1k) has B-frag
// granularity k=g*4+b — exactly the S^T C/D layout. Per dt, two K=16 MFMAs
// (jt halves): B = own p[jt][0..3] packed bf16x4 (no cross-lane movement),
// A = V^T 8B frag via ds_read_b64. C/D layout identical to the K=32 shape,
// so acc/merge/epilogue unchanged. Fallback (no _1k builtin): R6 shuffle path.
//   K : row-major bf16 [32][64], addr = row*128 + (off ^ ((row&7)<<4))
//   Vt: transposed bf16, FULL-ADDRESS XOR: addr = (vc*64 + off) ^ ((vc&7)<<4)
//       (keys have no bits <16, so 8B/16B sub-chunks stay contiguous)
// LDS (32768 B): [0,16K) k[half][dbuf][4096] (merge overlays), [16K,32K) vt.
__global__ __launch_bounds__(512, 4)
void attn_alibi_kernel(const float* __restrict__ q,
                       const float* __restrict__ k,
                       const float* __restrict__ v,
                       float* __restrict__ out) {
    const int tid  = threadIdx.x;
    const int wave = tid >> 6;
    const int lane = tid & 63;
    const int col  = lane & 15;
    const int g    = lane >> 4;
    const int half = wave >> 2;
    const int w4   = wave & 3;

    const int h      = blockIdx.y;
    const int qbase  = blockIdx.x * 64 + w4 * 16;
    const int kstart = half * HALF_LEN;

    const float* qh = q + (size_t)h * SEQ_LEN * HEAD_DIM;
    const float* kh = k + (size_t)h * SEQ_LEN * HEAD_DIM;
    const float* vh = v + (size_t)h * SEQ_LEN * HEAD_DIM;
    float*       oh = out + (size_t)h * SEQ_LEN * HEAD_DIM;

    __shared__ alignas(16) char smem[32768];
    char* kbase  = smem + half * 8192;
    char* vtbase = smem + 16384 + half * 8192;

    const float LOG2E  = 1.4426950408889634f;
    const float scale2 = 0.125f * LOG2E;
    const float slope  = exp2f(-0.5f * (float)(h + 1));
    const float slope2 = slope * LOG2E;

    // ---- Q B-fragments: lane holds Q[qbase+col][c*32 + g*8 + b] ----
    bf16x8 qf[2];
    {
        const float* qr = qh + (size_t)(qbase + col) * HEAD_DIM + g * 8;
        #pragma unroll
        for (int c = 0; c < 2; ++c)
            #pragma unroll
            for (int b = 0; b < 8; ++b) qf[c][b] = (__bf16)qr[c * 32 + b];
    }

    // ALiBi: cb = slope2*((jt*16+g*4+r) - (qbase+col))
    float cb[2][4];
    #pragma unroll
    for (int jt = 0; jt < 2; ++jt)
        #pragma unroll
        for (int r = 0; r < 4; ++r)
            cb[jt][r] = slope2 * (float)(jt * 16 + g * 4 + r - (qbase + col));

    float m = -1e30f, l = 0.0f;
    f32x4 acc[4];
    #pragma unroll
    for (int dt = 0; dt < 4; ++dt) acc[dt] = (f32x4)0.0f;

    // ---- staging (256 threads per half stage that half's stream) ----
    const int hid  = tid & 255;
    const int krow = hid >> 3;
    const int kcol = (hid & 7) * 8;
    const float* ksrc = kh + (size_t)(kstart + krow) * HEAD_DIM + kcol;
    char* kdst = kbase + krow * 128 + ((kcol * 2) ^ ((krow & 7) << 4));

    const int vc = hid & 63;
    const int vr = (hid >> 6) * 8;
    const float* vsrc = vh + (size_t)(kstart + vr) * HEAD_DIM + vc;
    char* vtdst = vtbase + (((vc * 64) + (vr * 2)) ^ ((vc & 7) << 4));

    f32x4 kr0, kr1;
    float vv[8];

    // ---- prologue: stage tile 0 ----
    kr0 = *(const f32x4*)(ksrc);
    kr1 = *(const f32x4*)(ksrc + 4);
    #pragma unroll
    for (int j = 0; j < 8; ++j) vv[j] = vsrc[(size_t)j * HEAD_DIM];
    {
        bf16x8 kb16, vb16;
        #pragma unroll
        for (int b = 0; b < 4; ++b) { kb16[b] = (__bf16)kr0[b]; kb16[4 + b] = (__bf16)kr1[b]; }
        #pragma unroll
        for (int j = 0; j < 8; ++j) vb16[j] = (__bf16)vv[j];
        *(bf16x8*)(kdst)  = kb16;
        *(bf16x8*)(vtdst) = vb16;
    }
    __syncthreads();

    for (int t = 0; t < NTILES; ++t) {
        const int kb  = kstart + t * KVBLK;
        const int buf = t & 1;
        const char* kbuf  = kbase + buf * 4096;
        const char* vtbuf = vtbase + buf * 4096;

        // ---- S^T = K Q^T (swapped operands) ----
        f32x4 sacc[2];
        sacc[0] = (f32x4)0.0f;
        sacc[1] = (f32x4)0.0f;
        #pragma unroll
        for (int jt = 0; jt < 2; ++jt) {
            const int row = jt * 16 + col;
            #pragma unroll
            for (int c = 0; c < 2; ++c) {
                bf16x8 kf = *(const bf16x8*)(kbuf + row * 128
                                             + ((c * 64 + g * 16) ^ ((row & 7) << 4)));
                sacc[jt] = __builtin_amdgcn_mfma_f32_16x16x32_bf16(kf, qf[c], sacc[jt], 0, 0, 0);
            }
        }

        // ---- issue next-tile staging loads ----
        if (t + 1 < NTILES) {
            const float* ks = ksrc + (size_t)(t + 1) * KVBLK * HEAD_DIM;
            const float* vs = vsrc + (size_t)(t + 1) * KVBLK * HEAD_DIM;
            kr0 = *(const f32x4*)(ks);
            kr1 = *(const f32x4*)(ks + 4);
            #pragma unroll
            for (int j = 0; j < 8; ++j) vv[j] = vs[(size_t)j * HEAD_DIM];
        }

        // ---- scale + alibi (base-2); lane holds s[k-local] for its q-row ----
        const float skb = slope2 * (float)kb;
        float s[2][4];
        #pragma unroll
        for (int jt = 0; jt < 2; ++jt)
            #pragma unroll
            for (int r = 0; r < 4; ++r)
                s[jt][r] = sacc[jt][r] * scale2 + (cb[jt][r] + skb);

        // ---- online softmax: scalar per lane, 2+2 shfl across g-groups ----
        float x = s[0][0];
        #pragma unroll
        for (int jt = 0; jt < 2; ++jt)
            #pragma unroll
            for (int r = 0; r < 4; ++r) x = fmaxf(x, s[jt][r]);
        x = fmaxf(x, __shfl_xor(x, 16));
        x = fmaxf(x, __shfl_xor(x, 32));
        float mn    = fmaxf(m, x);
        float alpha = __builtin_amdgcn_exp2f(m - mn);
        m = mn;
        float p[2][4], y = 0.0f;
        #pragma unroll
        for (int jt = 0; jt < 2; ++jt)
            #pragma unroll
            for (int r = 0; r < 4; ++r) {
                p[jt][r] = __builtin_amdgcn_exp2f(s[jt][r] - mn);
                y += p[jt][r];
            }
        y += __shfl_xor(y, 16);
        y += __shfl_xor(y, 32);
        l = l * alpha + y;
        #pragma unroll
        for (int dt = 0; dt < 4; ++dt) acc[dt] *= alpha;

#if HAVE_MFMA16
        // ---- ZERO-SHUFFLE PV: two K=16 MFMAs per dt; B = own p[jt][*] ----
        bf16x4 pf0, pf1;
        #pragma unroll
        for (int b = 0; b < 4; ++b) { pf0[b] = (__bf16)p[0][b]; pf1[b] = (__bf16)p[1][b]; }
        const s16x4 pb0 = __builtin_bit_cast(s16x4, pf0);
        const s16x4 pb1 = __builtin_bit_cast(s16x4, pf1);
        #pragma unroll
        for (int dt = 0; dt < 4; ++dt) {
            const int vrow = dt * 16 + col;
            const int rb   = vrow * 64;
            const int swz  = (vrow & 7) << 4;
            bf16x4 vf0 = *(const bf16x4*)(vtbuf + ((rb + g * 8) ^ swz));
            bf16x4 vf1 = *(const bf16x4*)(vtbuf + ((rb + 32 + g * 8) ^ swz));
            acc[dt] = __builtin_amdgcn_mfma_f32_16x16x16bf16_1k(
                __builtin_bit_cast(s16x4, vf0), pb0, acc[dt], 0, 0, 0);
            acc[dt] = __builtin_amdgcn_mfma_f32_16x16x16bf16_1k(
                __builtin_bit_cast(s16x4, vf1), pb1, acc[dt], 0, 0, 0);
        }
#else
        // ---- fallback: R6 pack + 8-shfl permute + K=32 PV ----
        unsigned pk00 = pkbf(p[0][0], p[0][1]);
        unsigned pk01 = pkbf(p[0][2], p[0][3]);
        unsigned pk10 = pkbf(p[1][0], p[1][1]);
        unsigned pk11 = pkbf(p[1][2], p[1][3]);
        const int srcA = col + ((g & 1) << 5);
        const int srcB = srcA + 16;
        unsigned a00 = __shfl(pk00, srcA), a01 = __shfl(pk01, srcA);
        unsigned a10 = __shfl(pk10, srcA), a11 = __shfl(pk11, srcA);
        unsigned b00 = __shfl(pk00, srcB), b01 = __shfl(pk01, srcB);
        unsigned b10 = __shfl(pk10, srcB), b11 = __shfl(pk11, srcB);
        const bool hi = g >= 2;
        u32x4 pu;
        pu[0] = hi ? a10 : a00;
        pu[1] = hi ? a11 : a01;
        pu[2] = hi ? b10 : b00;
        pu[3] = hi ? b11 : b01;
        bf16x8 pf = __builtin_bit_cast(bf16x8, pu);
        #pragma unroll
        for (int dt = 0; dt < 4; ++dt) {
            const int vrow = dt * 16 + col;
            bf16x8 vf = *(const bf16x8*)(vtbuf
                            + ((vrow * 64 + g * 16) ^ ((vrow & 7) << 4)));
            acc[dt] = __builtin_amdgcn_mfma_f32_16x16x32_bf16(vf, pf, acc[dt], 0, 0, 0);
        }
#endif

        // ---- write next tile into the other LDS buffer ----
        if (t + 1 < NTILES) {
            bf16x8 kb16, vb16;
            #pragma unroll
            for (int b = 0; b < 4; ++b) { kb16[b] = (__bf16)kr0[b]; kb16[4 + b] = (__bf16)kr1[b]; }
            #pragma unroll
            for (int j = 0; j < 8; ++j) vb16[j] = (__bf16)vv[j];
            *(bf16x8*)(kdst  + ((t + 1) & 1) * 4096) = kb16;
            *(bf16x8*)(vtdst + ((t + 1) & 1) * 4096) = vb16;
        }
        __syncthreads();
    }

    // ---- merge halves (flash combine in O^T layout, base-2 domain) ----
    float* eacc = (float*)smem;            // [w4][q=col 16][d 64]
    float* eml  = (float*)(smem + 16384);  // [w4*16+col]*2

    if (half == 1) {
        #pragma unroll
        for (int dt = 0; dt < 4; ++dt)
            *(f32x4*)(eacc + w4 * 1024 + col * 64 + dt * 16 + g * 4) = acc[dt];
        if (g == 0) {
            eml[(w4 * 16 + col) * 2 + 0] = m;
            eml[(w4 * 16 + col) * 2 + 1] = l;
        }
    }
    __syncthreads();
    if (half == 0) {
        float m2 = eml[(w4 * 16 + col) * 2 + 0];
        float l2 = eml[(w4 * 16 + col) * 2 + 1];
        float mm = fmaxf(m, m2);
        float a1 = __builtin_amdgcn_exp2f(m - mm);
        float a2 = __builtin_amdgcn_exp2f(m2 - mm);
        float inv = 1.0f / (l * a1 + l2 * a2);
        float* orow = oh + (size_t)(qbase + col) * HEAD_DIM;
        #pragma unroll
        for (int dt = 0; dt < 4; ++dt) {
            f32x4 o2 = *(const f32x4*)(eacc + w4 * 1024 + col * 64 + dt * 16 + g * 4);
            f32x4 res = (acc[dt] * a1 + o2 * a2) * inv;
            *(f32x4*)(orow + dt * 16 + g * 4) = res;
        }
    }
}

extern "C" void kernel_launch(void* const* d_in, const int* in_sizes, int n_in,
                              void* d_out, int out_size, void* d_ws, size_t ws_size,
                              hipStream_t stream) {
    const float* q = (const float*)d_in[0];
    const float* k = (const float*)d_in[1];
    const float* v = (const float*)d_in[2];
    float* out = (float*)d_out;

    dim3 grid(SEQ_LEN / 64, N_HEADS, 1);
    dim3 block(512, 1, 1);
    attn_alibi_kernel<<<grid, block, 0, stream>>>(q, k, v, out);
}